// Round 4
// baseline (284.812 us; speedup 1.0000x reference)
//
#include <hip/hip_runtime.h>

#define S_LEN 2048
#define NHQ 8
#define NKV 2
#define HD 256
#define KVB 32

typedef __attribute__((ext_vector_type(8))) short bf16x8;
typedef __attribute__((ext_vector_type(4))) short bf16x4;
typedef __attribute__((ext_vector_type(4))) float f32x4;
typedef __attribute__((ext_vector_type(16))) float f32x16;
typedef __attribute__((ext_vector_type(4))) unsigned u32x4;

__device__ __forceinline__ short f2bf(float f) {
    unsigned u = __builtin_bit_cast(unsigned, f);
    u += 0x7FFFu + ((u >> 16) & 1u);
    return (short)(u >> 16);
}
__device__ __forceinline__ float bf2f(short s) {
    unsigned u = ((unsigned)(unsigned short)s) << 16;
    return __builtin_bit_cast(float, u);
}
__device__ __forceinline__ unsigned cvtpk(float a, float b) {
    unsigned r;
    asm("v_cvt_pk_bf16_f32 %0, %1, %2" : "=v"(r) : "v"(a), "v"(b));
    return r;
}
__device__ __forceinline__ void gload16(const short* g, short* l) {
    __builtin_amdgcn_global_load_lds((const __attribute__((address_space(1))) unsigned*)g,
                                     (__attribute__((address_space(3))) unsigned*)l, 16, 0, 0);
}
__device__ __forceinline__ float bperm(int srclane, float v) {
    return __builtin_bit_cast(float,
        __builtin_amdgcn_ds_bpermute(srclane * 4, __builtin_bit_cast(int, v)));
}

// ---------------- fp32 -> bf16 convert ----------------
__global__ __launch_bounds__(256) void cvt_kernel(const float* __restrict__ in,
                                                  short* __restrict__ out, int n) {
    int i = (blockIdx.x * 256 + threadIdx.x) * 4;
    if (i + 3 < n) {
        float4 f = *(const float4*)(in + i);
        bf16x4 o;
        o[0] = f2bf(f.x); o[1] = f2bf(f.y); o[2] = f2bf(f.z); o[3] = f2bf(f.w);
        *(bf16x4*)(out + i) = o;
    }
}

// ---------------- fp32 W[K][N] -> bf16 Wt[N][K] (convert + transpose) -------
__global__ __launch_bounds__(256) void wt_kernel(const float* __restrict__ in,
                                                 short* __restrict__ out,
                                                 int K, int N) {
    __shared__ short tile[64][72];
    int n0 = blockIdx.x * 64, k0 = blockIdx.y * 64;
    int t = threadIdx.x;
    #pragma unroll
    for (int i = 0; i < 16; i++) {
        int flat = i * 256 + t; int r = flat >> 6, c = flat & 63;
        tile[r][c] = f2bf(in[(long)(k0 + r) * N + n0 + c]);
    }
    __syncthreads();
    #pragma unroll
    for (int i = 0; i < 16; i++) {
        int flat = i * 256 + t; int r = flat >> 6, c = flat & 63;
        out[(long)(n0 + r) * K + k0 + c] = tile[c][r];
    }
}

// ---------------- m97-style GEMM: C[M][N] = A[M][K] @ Bt[N][K]^T ------------
template<int BN, int WRITE_BF16>
__global__ __launch_bounds__(256) void gemm_bt(const short* __restrict__ A,
                                               const short* __restrict__ Bt,
                                               void* __restrict__ Cv,
                                               int M, int N, int K) {
    constexpr int NI = BN / 32;          // B-frags per wave
    __shared__ short As[128 * 32];
    __shared__ short Bs[BN * 32];
    const int t = threadIdx.x;
    const int lane = t & 63, w = t >> 6;
    const int lr = lane & 15, lg = lane >> 4;
    const int m0 = blockIdx.y * 128, n0 = blockIdx.x * BN;
    const int wm = (w >> 1) * 64, wn = (w & 1) * (BN / 2);

    f32x4 acc[4][NI];
    #pragma unroll
    for (int i = 0; i < 4; i++)
        #pragma unroll
        for (int j = 0; j < NI; j++) acc[i][j] = (f32x4){0.f, 0.f, 0.f, 0.f};

    for (int k0 = 0; k0 < K; k0 += 32) {
        __syncthreads();
        #pragma unroll
        for (int r = 0; r < 2; r++) {            // A tile: 128x32 = 8 KB
            int sbase = r * 2048 + w * 512;
            int srow = (sbase + lane * 8) >> 5, scol = (sbase + lane * 8) & 31;
            gload16(A + (long)(m0 + srow) * K + k0 + scol, &As[sbase]);
        }
        #pragma unroll
        for (int r = 0; r < BN / 64; r++) {      // B tile: BNx32
            int sbase = r * 2048 + w * 512;
            int srow = (sbase + lane * 8) >> 5, scol = (sbase + lane * 8) & 31;
            gload16(Bt + (long)(n0 + srow) * K + k0 + scol, &Bs[sbase]);
        }
        __syncthreads();
        bf16x8 af[4], bfr[NI];
        #pragma unroll
        for (int mi = 0; mi < 4; mi++)
            af[mi] = *(const bf16x8*)&As[(wm + mi * 16 + lr) * 32 + lg * 8];
        #pragma unroll
        for (int ni = 0; ni < NI; ni++)
            bfr[ni] = *(const bf16x8*)&Bs[(wn + ni * 16 + lr) * 32 + lg * 8];
        #pragma unroll
        for (int mi = 0; mi < 4; mi++)
            #pragma unroll
            for (int ni = 0; ni < NI; ni++)
                acc[mi][ni] = __builtin_amdgcn_mfma_f32_16x16x32_bf16(af[mi], bfr[ni], acc[mi][ni], 0, 0, 0);
    }
    #pragma unroll
    for (int mi = 0; mi < 4; mi++)
    #pragma unroll
    for (int ni = 0; ni < NI; ni++)
    #pragma unroll
    for (int r = 0; r < 4; r++) {
        long row = m0 + wm + mi * 16 + lg * 4 + r;
        long col = n0 + wn + ni * 16 + lr;
        float v = acc[mi][ni][r];
        if (WRITE_BF16) ((short*)Cv)[row * N + col] = f2bf(v);
        else            ((float*)Cv)[row * N + col] = v;
    }
}

// ---------------- RMSNorm + partial RoPE (+ optional score prescale) --------
__global__ __launch_bounds__(256) void norm_rope_kernel(
    const short* __restrict__ in, short* __restrict__ out,
    const float* __restrict__ w, const float* __restrict__ cosb,
    const float* __restrict__ sinb, int H, long ob, long oh, long os,
    float scale) {
    int vec = blockIdx.x * 4 + (threadIdx.x >> 6);
    int lane = threadIdx.x & 63;
    int token = vec / H, head = vec % H;
    int b = token / S_LEN, s = token % S_LEN;

    bf16x4 xv = *(const bf16x4*)(in + (long)vec * 256 + lane * 4);
    float x0 = bf2f(xv[0]), x1 = bf2f(xv[1]), x2 = bf2f(xv[2]), x3 = bf2f(xv[3]);
    float ss = x0 * x0 + x1 * x1 + x2 * x2 + x3 * x3;
    #pragma unroll
    for (int m = 1; m < 64; m <<= 1) ss += __shfl_xor(ss, m);
    float inv = rsqrtf(ss * (1.f / 256.f) + 1e-6f);

    float4 wv = *(const float4*)(w + lane * 4);
    float y0 = x0 * inv * (1.f + wv.x);
    float y1 = x1 * inv * (1.f + wv.y);
    float y2 = x2 * inv * (1.f + wv.z);
    float y3 = x3 * inv * (1.f + wv.w);

    if (lane < 16) {
        float2 c = *(const float2*)&cosb[s * 32 + lane * 2];
        float2 sn = *(const float2*)&sinb[s * 32 + lane * 2];
        float a0 = y0 * c.x - y1 * sn.x, b0 = y0 * sn.x + y1 * c.x;
        float a1 = y2 * c.y - y3 * sn.y, b1 = y2 * sn.y + y3 * c.y;
        y0 = a0; y1 = b0; y2 = a1; y3 = b1;
    }
    y0 *= scale; y1 *= scale; y2 *= scale; y3 *= scale;
    long oidx = (long)b * ob + (long)head * oh + (long)s * os + lane * 4;
    bf16x4 o; o[0] = f2bf(y0); o[1] = f2bf(y1); o[2] = f2bf(y2); o[3] = f2bf(y3);
    *(bf16x4*)(out + oidx) = o;
}

// ---------------- V transpose: vf[b][s][kv][d] -> vr[b][kv][d][s] ----------------
__global__ __launch_bounds__(256) void transpose_v_kernel(const short* __restrict__ vf,
                                                          short* __restrict__ vr) {
    __shared__ short tile[64][65];
    int s0 = blockIdx.x * 64, d0 = blockIdx.y * 64;
    int bkv = blockIdx.z; int b = bkv >> 1, kv = bkv & 1;
    int t = threadIdx.x;
    #pragma unroll
    for (int i = 0; i < 16; i++) {
        int flat = i * 256 + t; int si = flat >> 6, di = flat & 63;
        tile[si][di] = vf[(long)(b * S_LEN + s0 + si) * 512 + kv * 256 + d0 + di];
    }
    __syncthreads();
    #pragma unroll
    for (int i = 0; i < 16; i++) {
        int flat = i * 256 + t; int di = flat >> 6, si = flat & 63;
        vr[(long)(bkv * 256 + d0 + di) * S_LEN + s0 + si] = tile[si][di];
    }
}

// ---------------- flash attention: 1-wave blocks, register-direct K/V -------
// No LDS, no barriers. K/V frags loaded straight from L2, pipelined 1 tile ahead.
// Scores pre-scaled by 1/16 (folded into Q).
__global__ __launch_bounds__(64) void flash_kernel(const short* __restrict__ Q,
                                                   const short* __restrict__ Kt,
                                                   const short* __restrict__ Vt,
                                                   short* __restrict__ O) {
    int idx = blockIdx.x;
    // balanced mapping: CU gets qt in {a, 31-a, 32+a, 63-a} -> 130 tiles/CU const
    int p = idx >> 4, a = p & 15, kq = p >> 4;
    int qt = (kq == 0) ? a : (kq == 1) ? (31 - a) : (kq == 2) ? (32 + a) : (63 - a);
    int bh = idx & 15, h = bh & 7, b = bh >> 3;
    int kv = h >> 2;
    int lane = threadIdx.x & 63;
    int ln = lane & 31, hi = lane >> 5;
    int q0 = qt * 32;
    int qg = q0 + ln;                        // this lane's q row (score column)

    const short* Kb = Kt + (long)(b * NKV + kv) * S_LEN * HD;
    const short* Vb = Vt + (long)(b * NKV + kv) * HD * S_LEN;

    // Q fragments in registers: Q[q=ln][dc*16 + hi*8 + e]
    bf16x8 qf[16];
    {
        const short* qrow = Q + ((long)(b * S_LEN + qg) * NHQ + h) * HD + hi * 8;
        #pragma unroll
        for (int dc = 0; dc < 16; dc++) qf[dc] = *(const bf16x8*)&qrow[dc * 16];
    }

    f32x16 acc[8];
    #pragma unroll
    for (int i = 0; i < 8; i++)
        #pragma unroll
        for (int j = 0; j < 16; j++) acc[i][j] = 0.f;
    float m = -1e30f, l = 0.f;

    int nt = qt + 1;

    // K-frag: lane holds K[k0+ln][dc*16 + hi*8 ..+7]
    // V-frag: vf[db*2+half] = V^T[db*32+ln][k0 + half*16 + hi*8 ..+7]
    bf16x8 kf[16], vf[16];
    const short* kl = Kb + (long)ln * HD + hi * 8;
    const short* vl = Vb + (long)ln * S_LEN + hi * 8;
    #pragma unroll
    for (int dc = 0; dc < 16; dc++) kf[dc] = *(const bf16x8*)&kl[dc * 16];
    #pragma unroll
    for (int db = 0; db < 8; db++) {
        vf[db * 2]     = *(const bf16x8*)&vl[(long)db * 32 * S_LEN];
        vf[db * 2 + 1] = *(const bf16x8*)&vl[(long)db * 32 * S_LEN + 16];
    }

    for (int tt = 0; tt < nt; tt++) {
        int k0 = tt * KVB;

        // ---- QK^T (swapped): s = K * Q, D[key][q]; two chains to cut latency
        f32x16 sA, sB;
        #pragma unroll
        for (int j = 0; j < 16; j++) { sA[j] = 0.f; sB[j] = 0.f; }
        #pragma unroll
        for (int dc = 0; dc < 16; dc += 2) {
            sA = __builtin_amdgcn_mfma_f32_32x32x16_bf16(kf[dc],     qf[dc],     sA, 0, 0, 0);
            sB = __builtin_amdgcn_mfma_f32_32x32x16_bf16(kf[dc + 1], qf[dc + 1], sB, 0, 0, 0);
        }
        f32x16 s;
        #pragma unroll
        for (int j = 0; j < 16; j++) s[j] = sA[j] + sB[j];

        // ---- prefetch next K tile into kf (hidden under softmax + PV) ----
        if (tt + 1 < nt) {
            const short* kn = kl + (long)(k0 + KVB) * HD;
            #pragma unroll
            for (int dc = 0; dc < 16; dc++) kf[dc] = *(const bf16x8*)&kn[dc * 16];
        }

        // ---- mask + online softmax, fully in-register ----
        if (k0 + KVB - 1 > q0) {
            #pragma unroll
            for (int r = 0; r < 16; r++) {
                int key_g = k0 + (r & 3) + 8 * (r >> 2) + 4 * hi;
                if (key_g > qg) s[r] = -1e30f;
            }
        }
        float mt = s[0];
        #pragma unroll
        for (int r = 1; r < 16; r++) mt = fmaxf(mt, s[r]);
        mt = fmaxf(mt, __shfl_xor(mt, 32));
        float mn = m;
        if (!__all(mt <= m + 8.f)) {           // defer-max (T13)
            mn = fmaxf(m, mt);
            float f = __expf(m - mn);
            m = mn;
            float fr[16];
            #pragma unroll
            for (int r = 0; r < 16; r++)
                fr[r] = bperm((r & 3) + 8 * (r >> 2) + 4 * hi, f);
            #pragma unroll
            for (int i = 0; i < 8; i++)
                #pragma unroll
                for (int r = 0; r < 16; r++) acc[i][r] *= fr[r];
            l *= f;
        }
        float pr[16], ps = 0.f;
        #pragma unroll
        for (int r = 0; r < 16; r++) { pr[r] = __expf(s[r] - mn); ps += pr[r]; }
        ps += __shfl_xor(ps, 32);
        l += ps;

        // ---- P -> bf16 A-fragments via cvt_pk + permlane32_swap (T12) ----
        unsigned pw[8];
        #pragma unroll
        for (int kc = 0; kc < 2; kc++) {
            unsigned X = cvtpk(pr[kc * 8 + 0], pr[kc * 8 + 1]);
            unsigned Y = cvtpk(pr[kc * 8 + 4], pr[kc * 8 + 5]);
            unsigned Z = cvtpk(pr[kc * 8 + 2], pr[kc * 8 + 3]);
            unsigned W = cvtpk(pr[kc * 8 + 6], pr[kc * 8 + 7]);
            asm volatile("v_permlane32_swap_b32 %0, %1" : "+v"(X), "+v"(Y));
            asm volatile("v_permlane32_swap_b32 %0, %1" : "+v"(Z), "+v"(W));
            pw[kc * 4 + 0] = X; pw[kc * 4 + 1] = Z;
            pw[kc * 4 + 2] = Y; pw[kc * 4 + 3] = W;
        }
        u32x4 w0 = {pw[0], pw[1], pw[2], pw[3]};
        u32x4 w1 = {pw[4], pw[5], pw[6], pw[7]};
        bf16x8 pa0 = __builtin_bit_cast(bf16x8, w0);
        bf16x8 pa1 = __builtin_bit_cast(bf16x8, w1);

        // ---- PV: acc[db] += P * V, D[q][d], lane owns d column ----
        #pragma unroll
        for (int db = 0; db < 8; db++) {
            acc[db] = __builtin_amdgcn_mfma_f32_32x32x16_bf16(pa0, vf[db * 2],     acc[db], 0, 0, 0);
            acc[db] = __builtin_amdgcn_mfma_f32_32x32x16_bf16(pa1, vf[db * 2 + 1], acc[db], 0, 0, 0);
        }

        // ---- prefetch next V tile into vf (hidden under next QK + softmax) ----
        if (tt + 1 < nt) {
            const short* vn = vl + k0 + KVB;
            #pragma unroll
            for (int db = 0; db < 8; db++) {
                vf[db * 2]     = *(const bf16x8*)&vn[(long)db * 32 * S_LEN];
                vf[db * 2 + 1] = *(const bf16x8*)&vn[(long)db * 32 * S_LEN + 16];
            }
        }
    }

    // ---- epilogue: O[q][d] = acc / l ----
    float linv = 1.f / l;
    float lr[16];
    #pragma unroll
    for (int r = 0; r < 16; r++)
        lr[r] = bperm((r & 3) + 8 * (r >> 2) + 4 * hi, linv);
    #pragma unroll
    for (int db = 0; db < 8; db++)
        #pragma unroll
        for (int r = 0; r < 16; r++) {
            int qrow = q0 + (r & 3) + 8 * (r >> 2) + 4 * hi;
            O[(long)(b * S_LEN + qrow) * 2048 + h * HD + db * 32 + ln] =
                f2bf(acc[db][r] * lr[r]);
        }
}

extern "C" void kernel_launch(void* const* d_in, const int* in_sizes, int n_in,
                              void* d_out, int out_size, void* d_ws, size_t ws_size,
                              hipStream_t stream) {
    const float* x    = (const float*)d_in[0];
    const float* cosb = (const float*)d_in[1];
    const float* sinb = (const float*)d_in[2];
    // d_in[3] = mask: equivalent to causal; computed analytically in-kernel
    const float* wq   = (const float*)d_in[4];
    const float* wk   = (const float*)d_in[5];
    const float* wv   = (const float*)d_in[6];
    const float* wo   = (const float*)d_in[7];
    const float* qnw  = (const float*)d_in[8];
    const float* knw  = (const float*)d_in[9];
    float* out = (float*)d_out;

    char* ws = (char*)d_ws;
    short* xb  = (short*)(ws + 0);          // 4096x512   bf16
    short* wqt = (short*)(ws + 4194304);    // 2048x512   (transposed)
    short* wkt = (short*)(ws + 6291456);    // 512x512    (transposed)
    short* wvt = (short*)(ws + 6815744);    // 512x512    (transposed)
    short* wot = (short*)(ws + 7340032);    // 512x2048   (transposed)
    short* qf  = (short*)(ws + 9437184);    // 4096x2048 (q raw -> roped in place)
    short* kf  = (short*)(ws + 26214400);   // 4096x512
    short* vf  = (short*)(ws + 30408704);   // 4096x512
    short* kr  = (short*)(ws + 34603008);   // [b][kv][s][d]
    short* vr  = (short*)(ws + 38797312);   // [b][kv][d][s]
    short* ao  = (short*)(ws + 42991616);   // 4096x2048

    cvt_kernel<<<2048, 256, 0, stream>>>(x, xb, 2097152);
    wt_kernel<<<dim3(32, 8),  256, 0, stream>>>(wq, wqt, 512, 2048);
    wt_kernel<<<dim3(8, 8),   256, 0, stream>>>(wk, wkt, 512, 512);
    wt_kernel<<<dim3(8, 8),   256, 0, stream>>>(wv, wvt, 512, 512);
    wt_kernel<<<dim3(8, 32),  256, 0, stream>>>(wo, wot, 2048, 512);

    gemm_bt<128, 1><<<dim3(16, 32), 256, 0, stream>>>(xb, wqt, qf, 4096, 2048, 512);
    gemm_bt<64, 1><<<dim3(8, 32),   256, 0, stream>>>(xb, wkt, kf, 4096, 512, 512);
    gemm_bt<64, 1><<<dim3(8, 32),   256, 0, stream>>>(xb, wvt, vf, 4096, 512, 512);

    // Q gets the 1/sqrt(256) attention scale folded in for free
    norm_rope_kernel<<<8192, 256, 0, stream>>>(qf, qf, qnw, cosb, sinb, 8,
                                               4194304L, 256L, 2048L, 0.0625f);
    norm_rope_kernel<<<2048, 256, 0, stream>>>(kf, kr, knw, cosb, sinb, 2,
                                               1048576L, 524288L, 256L, 1.0f);
    transpose_v_kernel<<<dim3(32, 4, 4), 256, 0, stream>>>(vf, vr);

    flash_kernel<<<1024, 64, 0, stream>>>(qf, kr, vr, ao);

    gemm_bt<64, 0><<<dim3(8, 32), 256, 0, stream>>>(ao, wot, out, 4096, 512, 2048);
}

// Round 6
// 220.045 us; speedup vs baseline: 1.2943x; 1.2943x over previous
//
#include <hip/hip_runtime.h>

#define S_LEN 2048
#define NHQ 8
#define NKV 2
#define HD 256
#define KVB 32

typedef __attribute__((ext_vector_type(8))) short bf16x8;
typedef __attribute__((ext_vector_type(4))) short bf16x4;
typedef __attribute__((ext_vector_type(4))) float f32x4;
typedef __attribute__((ext_vector_type(16))) float f32x16;
typedef __attribute__((ext_vector_type(4))) unsigned u32x4;

__device__ __forceinline__ short f2bf(float f) {
    unsigned u = __builtin_bit_cast(unsigned, f);
    u += 0x7FFFu + ((u >> 16) & 1u);
    return (short)(u >> 16);
}
__device__ __forceinline__ float bf2f(short s) {
    unsigned u = ((unsigned)(unsigned short)s) << 16;
    return __builtin_bit_cast(float, u);
}
__device__ __forceinline__ unsigned cvtpk(float a, float b) {
    unsigned r;
    asm("v_cvt_pk_bf16_f32 %0, %1, %2" : "=v"(r) : "v"(a), "v"(b));
    return r;
}
__device__ __forceinline__ void gload16(const short* g, short* l) {
    __builtin_amdgcn_global_load_lds((const __attribute__((address_space(1))) unsigned*)g,
                                     (__attribute__((address_space(3))) unsigned*)l, 16, 0, 0);
}
__device__ __forceinline__ float bperm(int srclane, float v) {
    return __builtin_bit_cast(float,
        __builtin_amdgcn_ds_bpermute(srclane * 4, __builtin_bit_cast(int, v)));
}

// ---------------- fp32 -> bf16 convert ----------------
__global__ __launch_bounds__(256) void cvt_kernel(const float* __restrict__ in,
                                                  short* __restrict__ out, int n) {
    int i = (blockIdx.x * 256 + threadIdx.x) * 4;
    if (i + 3 < n) {
        float4 f = *(const float4*)(in + i);
        bf16x4 o;
        o[0] = f2bf(f.x); o[1] = f2bf(f.y); o[2] = f2bf(f.z); o[3] = f2bf(f.w);
        *(bf16x4*)(out + i) = o;
    }
}

// ---------------- fp32 W[K][N] -> bf16 Wt[N][K] (convert + transpose) -------
__global__ __launch_bounds__(256) void wt_kernel(const float* __restrict__ in,
                                                 short* __restrict__ out,
                                                 int K, int N) {
    __shared__ short tile[64][72];
    int n0 = blockIdx.x * 64, k0 = blockIdx.y * 64;
    int t = threadIdx.x;
    #pragma unroll
    for (int i = 0; i < 16; i++) {
        int flat = i * 256 + t; int r = flat >> 6, c = flat & 63;
        tile[r][c] = f2bf(in[(long)(k0 + r) * N + n0 + c]);
    }
    __syncthreads();
    #pragma unroll
    for (int i = 0; i < 16; i++) {
        int flat = i * 256 + t; int r = flat >> 6, c = flat & 63;
        out[(long)(n0 + r) * K + k0 + c] = tile[c][r];
    }
}

// ---------------- m97-style GEMM: C[M][N] = A[M][K] @ Bt[N][K]^T ------------
template<int BN, int WRITE_BF16>
__global__ __launch_bounds__(256) void gemm_bt(const short* __restrict__ A,
                                               const short* __restrict__ Bt,
                                               void* __restrict__ Cv,
                                               int M, int N, int K) {
    constexpr int NI = BN / 32;          // B-frags per wave
    __shared__ short As[128 * 32];
    __shared__ short Bs[BN * 32];
    const int t = threadIdx.x;
    const int lane = t & 63, w = t >> 6;
    const int lr = lane & 15, lg = lane >> 4;
    const int m0 = blockIdx.y * 128, n0 = blockIdx.x * BN;
    const int wm = (w >> 1) * 64, wn = (w & 1) * (BN / 2);

    f32x4 acc[4][NI];
    #pragma unroll
    for (int i = 0; i < 4; i++)
        #pragma unroll
        for (int j = 0; j < NI; j++) acc[i][j] = (f32x4){0.f, 0.f, 0.f, 0.f};

    for (int k0 = 0; k0 < K; k0 += 32) {
        __syncthreads();
        #pragma unroll
        for (int r = 0; r < 2; r++) {            // A tile: 128x32 = 8 KB
            int sbase = r * 2048 + w * 512;
            int srow = (sbase + lane * 8) >> 5, scol = (sbase + lane * 8) & 31;
            gload16(A + (long)(m0 + srow) * K + k0 + scol, &As[sbase]);
        }
        #pragma unroll
        for (int r = 0; r < BN / 64; r++) {      // B tile: BNx32
            int sbase = r * 2048 + w * 512;
            int srow = (sbase + lane * 8) >> 5, scol = (sbase + lane * 8) & 31;
            gload16(Bt + (long)(n0 + srow) * K + k0 + scol, &Bs[sbase]);
        }
        __syncthreads();
        bf16x8 af[4], bfr[NI];
        #pragma unroll
        for (int mi = 0; mi < 4; mi++)
            af[mi] = *(const bf16x8*)&As[(wm + mi * 16 + lr) * 32 + lg * 8];
        #pragma unroll
        for (int ni = 0; ni < NI; ni++)
            bfr[ni] = *(const bf16x8*)&Bs[(wn + ni * 16 + lr) * 32 + lg * 8];
        #pragma unroll
        for (int mi = 0; mi < 4; mi++)
            #pragma unroll
            for (int ni = 0; ni < NI; ni++)
                acc[mi][ni] = __builtin_amdgcn_mfma_f32_16x16x32_bf16(af[mi], bfr[ni], acc[mi][ni], 0, 0, 0);
    }
    #pragma unroll
    for (int mi = 0; mi < 4; mi++)
    #pragma unroll
    for (int ni = 0; ni < NI; ni++)
    #pragma unroll
    for (int r = 0; r < 4; r++) {
        long row = m0 + wm + mi * 16 + lg * 4 + r;
        long col = n0 + wn + ni * 16 + lr;
        float v = acc[mi][ni][r];
        if (WRITE_BF16) ((short*)Cv)[row * N + col] = f2bf(v);
        else            ((float*)Cv)[row * N + col] = v;
    }
}

// ---------------- RMSNorm + partial RoPE (+ optional score prescale) --------
// reads strided rows from the fused QKV output C
__global__ __launch_bounds__(256) void norm_rope_kernel(
    const short* __restrict__ in, short* __restrict__ out,
    const float* __restrict__ w, const float* __restrict__ cosb,
    const float* __restrict__ sinb, int H, long ldin, long cofs,
    long ob, long oh, long os, float scale) {
    int vec = blockIdx.x * 4 + (threadIdx.x >> 6);
    int lane = threadIdx.x & 63;
    int token = vec / H, head = vec % H;
    int b = token / S_LEN, s = token % S_LEN;

    bf16x4 xv = *(const bf16x4*)(in + (long)token * ldin + cofs + head * 256 + lane * 4);
    float x0 = bf2f(xv[0]), x1 = bf2f(xv[1]), x2 = bf2f(xv[2]), x3 = bf2f(xv[3]);
    float ss = x0 * x0 + x1 * x1 + x2 * x2 + x3 * x3;
    #pragma unroll
    for (int m = 1; m < 64; m <<= 1) ss += __shfl_xor(ss, m);
    float inv = rsqrtf(ss * (1.f / 256.f) + 1e-6f);

    float4 wv = *(const float4*)(w + lane * 4);
    float y0 = x0 * inv * (1.f + wv.x);
    float y1 = x1 * inv * (1.f + wv.y);
    float y2 = x2 * inv * (1.f + wv.z);
    float y3 = x3 * inv * (1.f + wv.w);

    if (lane < 16) {
        float2 c = *(const float2*)&cosb[s * 32 + lane * 2];
        float2 sn = *(const float2*)&sinb[s * 32 + lane * 2];
        float a0 = y0 * c.x - y1 * sn.x, b0 = y0 * sn.x + y1 * c.x;
        float a1 = y2 * c.y - y3 * sn.y, b1 = y2 * sn.y + y3 * c.y;
        y0 = a0; y1 = b0; y2 = a1; y3 = b1;
    }
    y0 *= scale; y1 *= scale; y2 *= scale; y3 *= scale;
    long oidx = (long)b * ob + (long)head * oh + (long)s * os + lane * 4;
    bf16x4 o; o[0] = f2bf(y0); o[1] = f2bf(y1); o[2] = f2bf(y2); o[3] = f2bf(y3);
    *(bf16x4*)(out + oidx) = o;
}

// ---------------- V transpose: C[token][2560+kv*256+d] -> vr[b][kv][d][s] ---
__global__ __launch_bounds__(256) void transpose_v_kernel(const short* __restrict__ C,
                                                          short* __restrict__ vr) {
    __shared__ short tile[64][65];
    int s0 = blockIdx.x * 64, d0 = blockIdx.y * 64;
    int bkv = blockIdx.z; int b = bkv >> 1, kv = bkv & 1;
    int t = threadIdx.x;
    #pragma unroll
    for (int i = 0; i < 16; i++) {
        int flat = i * 256 + t; int si = flat >> 6, di = flat & 63;
        tile[si][di] = C[(long)(b * S_LEN + s0 + si) * 3072 + 2560 + kv * 256 + d0 + di];
    }
    __syncthreads();
    #pragma unroll
    for (int i = 0; i < 16; i++) {
        int flat = i * 256 + t; int di = flat >> 6, si = flat & 63;
        vr[(long)(bkv * 256 + d0 + di) * S_LEN + s0 + si] = tile[si][di];
    }
}

// ---------------- flash attention: 2-wave, named A/B dbuf, counted vmcnt ----
// Scores pre-scaled by 1/16 (folded into Q).
__global__ __launch_bounds__(128) void flash_kernel(const short* __restrict__ Q,
                                                    const short* __restrict__ Kt,
                                                    const short* __restrict__ Vt,
                                                    short* __restrict__ O) {
    __shared__ short KsA[KVB * 256];   // [key][d] 512B rows, byte ^= (key&7)<<4
    __shared__ short VsA[256 * KVB];   // [d][key] 64B rows,  byte ^= (d&6)<<3
    __shared__ short KsB[KVB * 256];
    __shared__ short VsB[256 * KVB];

    int idx = blockIdx.x;
    // heavy-first / pair-balanced: first 256 blocks qt=31..16, rest qt=0..15
    int qt = (idx < 256) ? (31 - (idx >> 4)) : ((idx - 256) >> 4);
    int bh = idx & 15, h = bh & 7, b = bh >> 3;
    int kv = h >> 2;
    int t = threadIdx.x, lane = t & 63, w = t >> 6;
    int ln = lane & 31, hi = lane >> 5;
    int q0 = qt * 64 + w * 32;
    int qg = q0 + ln;                        // this lane's q row (score column)

    const short* Kb = Kt + (long)(b * NKV + kv) * S_LEN * HD;
    const short* Vb = Vt + (long)(b * NKV + kv) * HD * S_LEN;

    // Q fragments in registers: Q[q=ln][dc*16 + hi*8 + e]
    bf16x8 qf[16];
    {
        const short* qrow = Q + ((long)(b * S_LEN + qg) * NHQ + h) * HD + hi * 8;
        #pragma unroll
        for (int dc = 0; dc < 16; dc++) qf[dc] = *(const bf16x8*)&qrow[dc * 16];
    }

    f32x16 acc[8];
    #pragma unroll
    for (int i = 0; i < 8; i++)
        #pragma unroll
        for (int j = 0; j < 16; j++) acc[i][j] = 0.f;
    float m = -1e30f, l = 0.f;

    int nt = 2 * qt + 2;                     // always even, >= 2

    auto stage = [&](short* Ks, short* Vs, int tile) {   // 16 loads/thread
        int k0 = tile * KVB;
        #pragma unroll
        for (int c = 0; c < 8; c++) {
            int o = (w * 8 + c) * 1024 + lane * 16;      // byte offset in Ks
            int key = o >> 9, db = o & 511;
            gload16(Kb + (long)(k0 + key) * HD + ((db ^ ((key & 7) << 4)) >> 1),
                    &Ks[(w * 8 + c) * 512]);
        }
        #pragma unroll
        for (int c = 0; c < 8; c++) {
            int o = (w * 8 + c) * 1024 + lane * 16;      // byte offset in Vs
            int d = o >> 6, kb = o & 63;
            gload16(Vb + (long)d * S_LEN + k0 + ((kb ^ ((d & 6) << 3)) >> 1),
                    &Vs[(w * 8 + c) * 512]);
        }
    };

    auto compute = [&](const short* Ks, const short* Vs, int k0) {
        // ---- QK^T (swapped): s = K * Q, D[key][q]; 2 chains ----
        f32x16 sA, sB;
        #pragma unroll
        for (int j = 0; j < 16; j++) { sA[j] = 0.f; sB[j] = 0.f; }
        __builtin_amdgcn_s_setprio(1);
        #pragma unroll
        for (int dc = 0; dc < 16; dc += 2) {
            int kb0 = (dc * 32 + hi * 16) ^ ((ln & 7) << 4);
            int kb1 = ((dc + 1) * 32 + hi * 16) ^ ((ln & 7) << 4);
            bf16x8 kf0 = *(const bf16x8*)((const char*)Ks + ln * 512 + kb0);
            bf16x8 kf1 = *(const bf16x8*)((const char*)Ks + ln * 512 + kb1);
            sA = __builtin_amdgcn_mfma_f32_32x32x16_bf16(kf0, qf[dc],     sA, 0, 0, 0);
            sB = __builtin_amdgcn_mfma_f32_32x32x16_bf16(kf1, qf[dc + 1], sB, 0, 0, 0);
        }
        __builtin_amdgcn_s_setprio(0);
        f32x16 s;
        #pragma unroll
        for (int j = 0; j < 16; j++) s[j] = sA[j] + sB[j];

        // ---- mask + online softmax, fully in-register ----
        if (k0 + KVB - 1 > q0) {
            #pragma unroll
            for (int r = 0; r < 16; r++) {
                int key_g = k0 + (r & 3) + 8 * (r >> 2) + 4 * hi;
                if (key_g > qg) s[r] = -1e30f;
            }
        }
        float mt = s[0];
        #pragma unroll
        for (int r = 1; r < 16; r++) mt = fmaxf(mt, s[r]);
        mt = fmaxf(mt, __shfl_xor(mt, 32));
        float mn = m;
        if (!__all(mt <= m + 8.f)) {           // defer-max (T13)
            mn = fmaxf(m, mt);
            float f = __expf(m - mn);
            m = mn;
            float fr[16];
            #pragma unroll
            for (int r = 0; r < 16; r++)
                fr[r] = bperm((r & 3) + 8 * (r >> 2) + 4 * hi, f);
            #pragma unroll
            for (int i = 0; i < 8; i++)
                #pragma unroll
                for (int r = 0; r < 16; r++) acc[i][r] *= fr[r];
            l *= f;
        }
        float p[16], ps = 0.f;
        #pragma unroll
        for (int r = 0; r < 16; r++) { p[r] = __expf(s[r] - mn); ps += p[r]; }
        ps += __shfl_xor(ps, 32);
        l += ps;

        // ---- P -> bf16 A-fragments via cvt_pk + permlane32_swap (T12) ----
        unsigned pw[8];
        #pragma unroll
        for (int kc = 0; kc < 2; kc++) {
            unsigned X = cvtpk(p[kc * 8 + 0], p[kc * 8 + 1]);
            unsigned Y = cvtpk(p[kc * 8 + 4], p[kc * 8 + 5]);
            unsigned Z = cvtpk(p[kc * 8 + 2], p[kc * 8 + 3]);
            unsigned W = cvtpk(p[kc * 8 + 6], p[kc * 8 + 7]);
            asm volatile("v_permlane32_swap_b32 %0, %1" : "+v"(X), "+v"(Y));
            asm volatile("v_permlane32_swap_b32 %0, %1" : "+v"(Z), "+v"(W));
            pw[kc * 4 + 0] = X; pw[kc * 4 + 1] = Z;
            pw[kc * 4 + 2] = Y; pw[kc * 4 + 3] = W;
        }
        u32x4 w0v = {pw[0], pw[1], pw[2], pw[3]};
        u32x4 w1v = {pw[4], pw[5], pw[6], pw[7]};
        bf16x8 pa0 = __builtin_bit_cast(bf16x8, w0v);
        bf16x8 pa1 = __builtin_bit_cast(bf16x8, w1v);

        // ---- PV: acc[db] += P * V, D[q][d], lane owns d column ----
        __builtin_amdgcn_s_setprio(1);
        #pragma unroll
        for (int db = 0; db < 8; db++) {
            int drow = db * 32 + ln;
            int sw = (drow & 6) << 3;
            bf16x8 vf0 = *(const bf16x8*)((const char*)Vs + drow * 64 + ((hi * 16) ^ sw));
            bf16x8 vf1 = *(const bf16x8*)((const char*)Vs + drow * 64 + ((32 + hi * 16) ^ sw));
            acc[db] = __builtin_amdgcn_mfma_f32_32x32x16_bf16(pa0, vf0, acc[db], 0, 0, 0);
            acc[db] = __builtin_amdgcn_mfma_f32_32x32x16_bf16(pa1, vf1, acc[db], 0, 0, 0);
        }
        __builtin_amdgcn_s_setprio(0);
    };

    #define VW16 asm volatile("s_waitcnt vmcnt(16)" ::: "memory")
    #define VW0  asm volatile("s_waitcnt vmcnt(0)" ::: "memory")
    #define BAR  __builtin_amdgcn_s_barrier()

    stage(KsA, VsA, 0);
    stage(KsB, VsB, 1);

    int tt = 0;
    for (; tt + 2 < nt; tt += 2) {
        VW16; BAR;
        if (tt * KVB <= q0 + 31) compute(KsA, VsA, tt * KVB);
        BAR;
        stage(KsA, VsA, tt + 2);
        __builtin_amdgcn_sched_barrier(0);
        VW16; BAR;
        if ((tt + 1) * KVB <= q0 + 31) compute(KsB, VsB, (tt + 1) * KVB);
        BAR;
        stage(KsB, VsB, tt + 3);
        __builtin_amdgcn_sched_barrier(0);
    }
    // tail: tt == nt-2
    VW16; BAR;
    if ((nt - 2) * KVB <= q0 + 31) compute(KsA, VsA, (nt - 2) * KVB);
    VW0; BAR;
    if ((nt - 1) * KVB <= q0 + 31) compute(KsB, VsB, (nt - 1) * KVB);

    #undef VW16
    #undef VW0
    #undef BAR

    // ---- epilogue: O[q][d] = acc / l ----
    float linv = 1.f / l;
    float lr[16];
    #pragma unroll
    for (int r = 0; r < 16; r++)
        lr[r] = bperm((r & 3) + 8 * (r >> 2) + 4 * hi, linv);
    #pragma unroll
    for (int db = 0; db < 8; db++)
        #pragma unroll
        for (int r = 0; r < 16; r++) {
            int qrow = q0 + (r & 3) + 8 * (r >> 2) + 4 * hi;
            O[(long)(b * S_LEN + qrow) * 2048 + h * HD + db * 32 + ln] =
                f2bf(acc[db][r] * lr[r]);
        }
}

extern "C" void kernel_launch(void* const* d_in, const int* in_sizes, int n_in,
                              void* d_out, int out_size, void* d_ws, size_t ws_size,
                              hipStream_t stream) {
    const float* x    = (const float*)d_in[0];
    const float* cosb = (const float*)d_in[1];
    const float* sinb = (const float*)d_in[2];
    // d_in[3] = mask: equivalent to causal; computed analytically in-kernel
    const float* wq   = (const float*)d_in[4];
    const float* wk   = (const float*)d_in[5];
    const float* wv   = (const float*)d_in[6];
    const float* wo   = (const float*)d_in[7];
    const float* qnw  = (const float*)d_in[8];
    const float* knw  = (const float*)d_in[9];
    float* out = (float*)d_out;

    char* ws = (char*)d_ws;
    short* xb   = (short*)(ws + 0);          // 4096x512 bf16               [0, 4194304)
    short* wfus = (short*)(ws + 4194304);    // [3072][512] wq|wk|wv^T      [4194304, 7340032)
    short* wot  = (short*)(ws + 7340032);    // [512][2048] wo^T            [7340032, 9437184)
    short* C    = (short*)(ws + 9437184);    // 4096x3072 fused QKV out     [9437184, 34603008)
    short* ao   = (short*)(ws + 9437184);    // flash out aliases C (dead)
    short* qro  = (short*)(ws + 34603008);   // 4096x2048 roped Q           [34603008, 51380224)
    short* kr   = (short*)(ws + 51380224);   // [b][kv][s][d] 4 MB          [51380224, 55574528)
    short* vr   = (short*)(ws + 55574528);   // [b][kv][d][s] 4 MB          [55574528, 59768832)

    cvt_kernel<<<2048, 256, 0, stream>>>(x, xb, 2097152);
    wt_kernel<<<dim3(32, 8), 256, 0, stream>>>(wq, wfus,              512, 2048);
    wt_kernel<<<dim3(8, 8),  256, 0, stream>>>(wk, wfus + 2048 * 512, 512, 512);
    wt_kernel<<<dim3(8, 8),  256, 0, stream>>>(wv, wfus + 2560 * 512, 512, 512);
    wt_kernel<<<dim3(8, 32), 256, 0, stream>>>(wo, wot, 2048, 512);

    // fused QKV projection: C[4096][3072]
    gemm_bt<128, 1><<<dim3(24, 32), 256, 0, stream>>>(xb, wfus, C, 4096, 3072, 512);

    // Q gets the 1/sqrt(256) attention scale folded in for free
    norm_rope_kernel<<<8192, 256, 0, stream>>>(C, qro, qnw, cosb, sinb, 8,
                                               3072L, 0L, 4194304L, 256L, 2048L, 0.0625f);
    norm_rope_kernel<<<2048, 256, 0, stream>>>(C, kr, knw, cosb, sinb, 2,
                                               3072L, 2048L, 1048576L, 524288L, 256L, 1.0f);
    transpose_v_kernel<<<dim3(32, 4, 4), 256, 0, stream>>>(C, vr);

    flash_kernel<<<512, 128, 0, stream>>>(qro, kr, vr, ao);

    gemm_bt<64, 0><<<dim3(8, 32), 256, 0, stream>>>(ao, wot, out, 4096, 512, 2048);
}

// Round 7
// 215.553 us; speedup vs baseline: 1.3213x; 1.0208x over previous
//
#include <hip/hip_runtime.h>

#define S_LEN 2048
#define NHQ 8
#define NKV 2
#define HD 256
#define KVB 32

typedef __attribute__((ext_vector_type(8))) short bf16x8;
typedef __attribute__((ext_vector_type(4))) short bf16x4;
typedef __attribute__((ext_vector_type(4))) float f32x4;
typedef __attribute__((ext_vector_type(16))) float f32x16;
typedef __attribute__((ext_vector_type(4))) unsigned u32x4;

__device__ __forceinline__ short f2bf(float f) {
    unsigned u = __builtin_bit_cast(unsigned, f);
    u += 0x7FFFu + ((u >> 16) & 1u);
    return (short)(u >> 16);
}
__device__ __forceinline__ float bf2f(short s) {
    unsigned u = ((unsigned)(unsigned short)s) << 16;
    return __builtin_bit_cast(float, u);
}
__device__ __forceinline__ unsigned cvtpk(float a, float b) {
    unsigned r;
    asm("v_cvt_pk_bf16_f32 %0, %1, %2" : "=v"(r) : "v"(a), "v"(b));
    return r;
}
__device__ __forceinline__ void gload16(const short* g, short* l) {
    __builtin_amdgcn_global_load_lds((const __attribute__((address_space(1))) unsigned*)g,
                                     (__attribute__((address_space(3))) unsigned*)l, 16, 0, 0);
}
__device__ __forceinline__ float bperm(int srclane, float v) {
    return __builtin_bit_cast(float,
        __builtin_amdgcn_ds_bpermute(srclane * 4, __builtin_bit_cast(int, v)));
}

// ---------------- fp32 -> bf16 convert ----------------
__global__ __launch_bounds__(256) void cvt_kernel(const float* __restrict__ in,
                                                  short* __restrict__ out, int n) {
    int i = (blockIdx.x * 256 + threadIdx.x) * 4;
    if (i + 3 < n) {
        float4 f = *(const float4*)(in + i);
        bf16x4 o;
        o[0] = f2bf(f.x); o[1] = f2bf(f.y); o[2] = f2bf(f.z); o[3] = f2bf(f.w);
        *(bf16x4*)(out + i) = o;
    }
}

// ---------------- fp32 W[K][N] -> bf16 Wt[N][K] (convert + transpose) -------
__global__ __launch_bounds__(256) void wt_kernel(const float* __restrict__ in,
                                                 short* __restrict__ out,
                                                 int K, int N) {
    __shared__ short tile[64][72];
    int n0 = blockIdx.x * 64, k0 = blockIdx.y * 64;
    int t = threadIdx.x;
    #pragma unroll
    for (int i = 0; i < 16; i++) {
        int flat = i * 256 + t; int r = flat >> 6, c = flat & 63;
        tile[r][c] = f2bf(in[(long)(k0 + r) * N + n0 + c]);
    }
    __syncthreads();
    #pragma unroll
    for (int i = 0; i < 16; i++) {
        int flat = i * 256 + t; int r = flat >> 6, c = flat & 63;
        out[(long)(n0 + r) * K + k0 + c] = tile[c][r];
    }
}

// ---------------- m97-style GEMM: C[M][N] = A[M][K] @ Bt[N][K]^T ------------
template<int BN, int WRITE_BF16>
__global__ __launch_bounds__(256) void gemm_bt(const short* __restrict__ A,
                                               const short* __restrict__ Bt,
                                               void* __restrict__ Cv,
                                               int M, int N, int K) {
    constexpr int NI = BN / 32;          // B-frags per wave
    __shared__ short As[128 * 32];
    __shared__ short Bs[BN * 32];
    const int t = threadIdx.x;
    const int lane = t & 63, w = t >> 6;
    const int lr = lane & 15, lg = lane >> 4;
    const int m0 = blockIdx.y * 128, n0 = blockIdx.x * BN;
    const int wm = (w >> 1) * 64, wn = (w & 1) * (BN / 2);

    f32x4 acc[4][NI];
    #pragma unroll
    for (int i = 0; i < 4; i++)
        #pragma unroll
        for (int j = 0; j < NI; j++) acc[i][j] = (f32x4){0.f, 0.f, 0.f, 0.f};

    for (int k0 = 0; k0 < K; k0 += 32) {
        __syncthreads();
        #pragma unroll
        for (int r = 0; r < 2; r++) {            // A tile: 128x32 = 8 KB
            int sbase = r * 2048 + w * 512;
            int srow = (sbase + lane * 8) >> 5, scol = (sbase + lane * 8) & 31;
            gload16(A + (long)(m0 + srow) * K + k0 + scol, &As[sbase]);
        }
        #pragma unroll
        for (int r = 0; r < BN / 64; r++) {      // B tile: BNx32
            int sbase = r * 2048 + w * 512;
            int srow = (sbase + lane * 8) >> 5, scol = (sbase + lane * 8) & 31;
            gload16(Bt + (long)(n0 + srow) * K + k0 + scol, &Bs[sbase]);
        }
        __syncthreads();
        bf16x8 af[4], bfr[NI];
        #pragma unroll
        for (int mi = 0; mi < 4; mi++)
            af[mi] = *(const bf16x8*)&As[(wm + mi * 16 + lr) * 32 + lg * 8];
        #pragma unroll
        for (int ni = 0; ni < NI; ni++)
            bfr[ni] = *(const bf16x8*)&Bs[(wn + ni * 16 + lr) * 32 + lg * 8];
        #pragma unroll
        for (int mi = 0; mi < 4; mi++)
            #pragma unroll
            for (int ni = 0; ni < NI; ni++)
                acc[mi][ni] = __builtin_amdgcn_mfma_f32_16x16x32_bf16(af[mi], bfr[ni], acc[mi][ni], 0, 0, 0);
    }
    #pragma unroll
    for (int mi = 0; mi < 4; mi++)
    #pragma unroll
    for (int ni = 0; ni < NI; ni++)
    #pragma unroll
    for (int r = 0; r < 4; r++) {
        long row = m0 + wm + mi * 16 + lg * 4 + r;
        long col = n0 + wn + ni * 16 + lr;
        float v = acc[mi][ni][r];
        if (WRITE_BF16) ((short*)Cv)[row * N + col] = f2bf(v);
        else            ((float*)Cv)[row * N + col] = v;
    }
}

// ---------------- RMSNorm + partial RoPE (+ optional score prescale) --------
// reads strided rows from the fused QKV output C
__global__ __launch_bounds__(256) void norm_rope_kernel(
    const short* __restrict__ in, short* __restrict__ out,
    const float* __restrict__ w, const float* __restrict__ cosb,
    const float* __restrict__ sinb, int H, long ldin, long cofs,
    long ob, long oh, long os, float scale) {
    int vec = blockIdx.x * 4 + (threadIdx.x >> 6);
    int lane = threadIdx.x & 63;
    int token = vec / H, head = vec % H;
    int b = token / S_LEN, s = token % S_LEN;

    bf16x4 xv = *(const bf16x4*)(in + (long)token * ldin + cofs + head * 256 + lane * 4);
    float x0 = bf2f(xv[0]), x1 = bf2f(xv[1]), x2 = bf2f(xv[2]), x3 = bf2f(xv[3]);
    float ss = x0 * x0 + x1 * x1 + x2 * x2 + x3 * x3;
    #pragma unroll
    for (int m = 1; m < 64; m <<= 1) ss += __shfl_xor(ss, m);
    float inv = rsqrtf(ss * (1.f / 256.f) + 1e-6f);

    float4 wv = *(const float4*)(w + lane * 4);
    float y0 = x0 * inv * (1.f + wv.x);
    float y1 = x1 * inv * (1.f + wv.y);
    float y2 = x2 * inv * (1.f + wv.z);
    float y3 = x3 * inv * (1.f + wv.w);

    if (lane < 16) {
        float2 c = *(const float2*)&cosb[s * 32 + lane * 2];
        float2 sn = *(const float2*)&sinb[s * 32 + lane * 2];
        float a0 = y0 * c.x - y1 * sn.x, b0 = y0 * sn.x + y1 * c.x;
        float a1 = y2 * c.y - y3 * sn.y, b1 = y2 * sn.y + y3 * c.y;
        y0 = a0; y1 = b0; y2 = a1; y3 = b1;
    }
    y0 *= scale; y1 *= scale; y2 *= scale; y3 *= scale;
    long oidx = (long)b * ob + (long)head * oh + (long)s * os + lane * 4;
    bf16x4 o; o[0] = f2bf(y0); o[1] = f2bf(y1); o[2] = f2bf(y2); o[3] = f2bf(y3);
    *(bf16x4*)(out + oidx) = o;
}

// ---------------- V transpose: C[token][2560+kv*256+d] -> vr[b][kv][d][s] ---
__global__ __launch_bounds__(256) void transpose_v_kernel(const short* __restrict__ C,
                                                          short* __restrict__ vr) {
    __shared__ short tile[64][65];
    int s0 = blockIdx.x * 64, d0 = blockIdx.y * 64;
    int bkv = blockIdx.z; int b = bkv >> 1, kv = bkv & 1;
    int t = threadIdx.x;
    #pragma unroll
    for (int i = 0; i < 16; i++) {
        int flat = i * 256 + t; int si = flat >> 6, di = flat & 63;
        tile[si][di] = C[(long)(b * S_LEN + s0 + si) * 3072 + 2560 + kv * 256 + d0 + di];
    }
    __syncthreads();
    #pragma unroll
    for (int i = 0; i < 16; i++) {
        int flat = i * 256 + t; int di = flat >> 6, si = flat & 63;
        vr[(long)(bkv * 256 + d0 + di) * S_LEN + s0 + si] = tile[si][di];
    }
}

// ---------------- flash attention: 8-wave blocks, 4-slot ring, parity split -
// Block = 128 q rows: 4 q-groups (32 rows) x 2 key-parities. 1 block/CU.
// Scores pre-scaled by 1/16 (folded into Q).
__global__ __launch_bounds__(512, 2) void flash_kernel(const short* __restrict__ Q,
                                                       const short* __restrict__ Kt,
                                                       const short* __restrict__ Vt,
                                                       short* __restrict__ O) {
    // [0,64K): K tiles (sp*2+p)*16KB ; [64K,128K): V tiles ; epilogue reuses all
    __shared__ __align__(16) char smem[132096];

    int idx = blockIdx.x;
    int a = idx >> 4;                       // q-block 0..15 (128 rows each)
    int bh = idx & 15, h = bh & 7, b = bh >> 3;
    int kv = h >> 2;
    int t = threadIdx.x, lane = t & 63, w = t >> 6;
    int g = w >> 1, p = w & 1;              // q-group, key parity
    int ln = lane & 31, hi = lane >> 5;
    int q0 = a * 128 + g * 32;
    int qg = q0 + ln;                        // this lane's q row (score column)

    const short* Kb = Kt + (long)(b * NKV + kv) * S_LEN * HD;
    const short* Vb = Vt + (long)(b * NKV + kv) * HD * S_LEN;

    // Q fragments in registers: Q[q=ln][dc*16 + hi*8 + e]
    bf16x8 qf[16];
    {
        const short* qrow = Q + ((long)(b * S_LEN + qg) * NHQ + h) * HD + hi * 8;
        #pragma unroll
        for (int dc = 0; dc < 16; dc++) qf[dc] = *(const bf16x8*)&qrow[dc * 16];
    }

    f32x16 acc[8];
    #pragma unroll
    for (int i = 0; i < 8; i++)
        #pragma unroll
        for (int j = 0; j < 16; j++) acc[i][j] = 0.f;
    float m = -1e30f, l = 0.f;

    const int nph  = 2 * a + 2;             // phases (tile pairs)
    const int Tmax = 4 * a + g;             // last tile this wave needs

    // stage tiles T0 (->parity slot 0) and T0+1 (->slot 1) of slot-pair sp
    auto stagepair = [&](int sp, int T0) {
        #pragma unroll
        for (int pp = 0; pp < 2; pp++) {
            int k0s = (T0 + pp) * KVB;
            short* Ktile = (short*)(smem + (sp * 2 + pp) * 16384);
            short* Vtile = (short*)(smem + 65536 + (sp * 2 + pp) * 16384);
            #pragma unroll
            for (int c = 0; c < 2; c++) {
                int o = c * 8192 + w * 1024 + lane * 16;   // byte offset in tile
                int key = o >> 9, db = o & 511;
                gload16(Kb + (long)(k0s + key) * HD + ((db ^ ((key & 7) << 4)) >> 1),
                        Ktile + (c * 8192 + w * 1024) / 2);
                int d = o >> 6, kb = o & 63;
                gload16(Vb + (long)d * S_LEN + k0s + ((kb ^ ((d & 6) << 3)) >> 1),
                        Vtile + (c * 8192 + w * 1024) / 2);
            }
        }
    };

    auto computeT = [&](int sp, int T) {
        const char* Ks = (const char*)smem + (sp * 2 + p) * 16384;
        const char* Vs = (const char*)smem + 65536 + (sp * 2 + p) * 16384;
        int k0 = T * KVB;
        // ---- QK^T (swapped): s = K * Q, D[key][q]; 2 chains ----
        f32x16 sA, sB;
        #pragma unroll
        for (int j = 0; j < 16; j++) { sA[j] = 0.f; sB[j] = 0.f; }
        __builtin_amdgcn_s_setprio(1);
        #pragma unroll
        for (int dc = 0; dc < 16; dc += 2) {
            int kb0 = (dc * 32 + hi * 16) ^ ((ln & 7) << 4);
            int kb1 = ((dc + 1) * 32 + hi * 16) ^ ((ln & 7) << 4);
            bf16x8 kf0 = *(const bf16x8*)(Ks + ln * 512 + kb0);
            bf16x8 kf1 = *(const bf16x8*)(Ks + ln * 512 + kb1);
            sA = __builtin_amdgcn_mfma_f32_32x32x16_bf16(kf0, qf[dc],     sA, 0, 0, 0);
            sB = __builtin_amdgcn_mfma_f32_32x32x16_bf16(kf1, qf[dc + 1], sB, 0, 0, 0);
        }
        __builtin_amdgcn_s_setprio(0);
        f32x16 s;
        #pragma unroll
        for (int j = 0; j < 16; j++) s[j] = sA[j] + sB[j];

        // ---- mask + online softmax, fully in-register ----
        if (k0 + KVB - 1 > q0) {
            #pragma unroll
            for (int r = 0; r < 16; r++) {
                int key_g = k0 + (r & 3) + 8 * (r >> 2) + 4 * hi;
                if (key_g > qg) s[r] = -1e30f;
            }
        }
        float mt = s[0];
        #pragma unroll
        for (int r = 1; r < 16; r++) mt = fmaxf(mt, s[r]);
        mt = fmaxf(mt, __shfl_xor(mt, 32));
        float mn = m;
        if (!__all(mt <= m + 8.f)) {           // defer-max (T13)
            mn = fmaxf(m, mt);
            float f = __expf(m - mn);
            m = mn;
            float fr[16];
            #pragma unroll
            for (int r = 0; r < 16; r++)
                fr[r] = bperm((r & 3) + 8 * (r >> 2) + 4 * hi, f);
            #pragma unroll
            for (int i = 0; i < 8; i++)
                #pragma unroll
                for (int r = 0; r < 16; r++) acc[i][r] *= fr[r];
            l *= f;
        }
        float pr[16], ps = 0.f;
        #pragma unroll
        for (int r = 0; r < 16; r++) { pr[r] = __expf(s[r] - mn); ps += pr[r]; }
        ps += __shfl_xor(ps, 32);
        l += ps;

        // ---- P -> bf16 A-fragments via cvt_pk + permlane32_swap (T12) ----
        unsigned pw[8];
        #pragma unroll
        for (int kc = 0; kc < 2; kc++) {
            unsigned X = cvtpk(pr[kc * 8 + 0], pr[kc * 8 + 1]);
            unsigned Y = cvtpk(pr[kc * 8 + 4], pr[kc * 8 + 5]);
            unsigned Z = cvtpk(pr[kc * 8 + 2], pr[kc * 8 + 3]);
            unsigned W = cvtpk(pr[kc * 8 + 6], pr[kc * 8 + 7]);
            asm volatile("v_permlane32_swap_b32 %0, %1" : "+v"(X), "+v"(Y));
            asm volatile("v_permlane32_swap_b32 %0, %1" : "+v"(Z), "+v"(W));
            pw[kc * 4 + 0] = X; pw[kc * 4 + 1] = Z;
            pw[kc * 4 + 2] = Y; pw[kc * 4 + 3] = W;
        }
        u32x4 w0v = {pw[0], pw[1], pw[2], pw[3]};
        u32x4 w1v = {pw[4], pw[5], pw[6], pw[7]};
        bf16x8 pa0 = __builtin_bit_cast(bf16x8, w0v);
        bf16x8 pa1 = __builtin_bit_cast(bf16x8, w1v);

        // ---- PV: acc[db] += P * V, D[q][d], lane owns d column ----
        __builtin_amdgcn_s_setprio(1);
        #pragma unroll
        for (int db = 0; db < 8; db++) {
            int drow = db * 32 + ln;
            int sw = (drow & 6) << 3;
            bf16x8 vf0 = *(const bf16x8*)(Vs + drow * 64 + ((hi * 16) ^ sw));
            bf16x8 vf1 = *(const bf16x8*)(Vs + drow * 64 + ((32 + hi * 16) ^ sw));
            acc[db] = __builtin_amdgcn_mfma_f32_32x32x16_bf16(pa0, vf0, acc[db], 0, 0, 0);
            acc[db] = __builtin_amdgcn_mfma_f32_32x32x16_bf16(pa1, vf1, acc[db], 0, 0, 0);
        }
        __builtin_amdgcn_s_setprio(0);
    };

    stagepair(0, 0);
    stagepair(1, 2);

    for (int ph = 0; ph < nph; ph++) {
        int sp = ph & 1;
        if (ph + 1 < nph) { asm volatile("s_waitcnt vmcnt(8)" ::: "memory"); }
        else              { asm volatile("s_waitcnt vmcnt(0)" ::: "memory"); }
        __builtin_amdgcn_s_barrier();
        int T = 2 * ph + p;
        if (T <= Tmax) computeT(sp, T);
        __builtin_amdgcn_s_barrier();
        if (ph + 2 < nph) stagepair(sp, 2 * ph + 4);
        __builtin_amdgcn_sched_barrier(0);
    }

    // ---- parity merge epilogue (ring LDS is dead) ----
    float* accb = (float*)smem;                 // [g][128][64]
    float* mlb  = (float*)(smem + 131072);      // m: [0,128), l: [128,256)
    if (p == 1) {
        #pragma unroll
        for (int db = 0; db < 8; db++)
            #pragma unroll
            for (int r = 0; r < 16; r++)
                accb[g * 8192 + (db * 16 + r) * 64 + hi * 32 + ln] = acc[db][r];
        if (hi == 0) { mlb[g * 32 + ln] = m; mlb[128 + g * 32 + ln] = l; }
    }
    __syncthreads();
    if (p == 0) {
        float m1 = mlb[g * 32 + ln], l1 = mlb[128 + g * 32 + ln];
        float M  = fmaxf(m, m1);
        float f0 = __expf(m - M), f1 = __expf(m1 - M);
        float lt = l * f0 + l1 * f1;
        float w0 = f0 / lt, w1 = f1 / lt;
        float fr0[16], fr1[16];
        #pragma unroll
        for (int r = 0; r < 16; r++) {
            int crow = (r & 3) + 8 * (r >> 2) + 4 * hi;
            fr0[r] = bperm(crow, w0);
            fr1[r] = bperm(crow, w1);
        }
        #pragma unroll
        for (int db = 0; db < 8; db++)
            #pragma unroll
            for (int r = 0; r < 16; r++) {
                float a1 = accb[g * 8192 + (db * 16 + r) * 64 + hi * 32 + ln];
                int qrow = q0 + (r & 3) + 8 * (r >> 2) + 4 * hi;
                O[(long)(b * S_LEN + qrow) * 2048 + h * HD + db * 32 + ln] =
                    f2bf(acc[db][r] * fr0[r] + a1 * fr1[r]);
            }
    }
}

extern "C" void kernel_launch(void* const* d_in, const int* in_sizes, int n_in,
                              void* d_out, int out_size, void* d_ws, size_t ws_size,
                              hipStream_t stream) {
    const float* x    = (const float*)d_in[0];
    const float* cosb = (const float*)d_in[1];
    const float* sinb = (const float*)d_in[2];
    // d_in[3] = mask: equivalent to causal; computed analytically in-kernel
    const float* wq   = (const float*)d_in[4];
    const float* wk   = (const float*)d_in[5];
    const float* wv   = (const float*)d_in[6];
    const float* wo   = (const float*)d_in[7];
    const float* qnw  = (const float*)d_in[8];
    const float* knw  = (const float*)d_in[9];
    float* out = (float*)d_out;

    char* ws = (char*)d_ws;
    short* xb   = (short*)(ws + 0);          // 4096x512 bf16               [0, 4194304)
    short* wfus = (short*)(ws + 4194304);    // [3072][512] wq|wk|wv^T      [4194304, 7340032)
    short* wot  = (short*)(ws + 7340032);    // [512][2048] wo^T            [7340032, 9437184)
    short* C    = (short*)(ws + 9437184);    // 4096x3072 fused QKV out     [9437184, 34603008)
    short* ao   = (short*)(ws + 9437184);    // flash out aliases C (dead)
    short* qro  = (short*)(ws + 34603008);   // 4096x2048 roped Q           [34603008, 51380224)
    short* kr   = (short*)(ws + 51380224);   // [b][kv][s][d] 4 MB          [51380224, 55574528)
    short* vr   = (short*)(ws + 55574528);   // [b][kv][d][s] 4 MB          [55574528, 59768832)

    cvt_kernel<<<2048, 256, 0, stream>>>(x, xb, 2097152);
    wt_kernel<<<dim3(32, 8), 256, 0, stream>>>(wq, wfus,              512, 2048);
    wt_kernel<<<dim3(8, 8),  256, 0, stream>>>(wk, wfus + 2048 * 512, 512, 512);
    wt_kernel<<<dim3(8, 8),  256, 0, stream>>>(wv, wfus + 2560 * 512, 512, 512);
    wt_kernel<<<dim3(8, 32), 256, 0, stream>>>(wo, wot, 2048, 512);

    // fused QKV projection: C[4096][3072]
    gemm_bt<128, 1><<<dim3(24, 32), 256, 0, stream>>>(xb, wfus, C, 4096, 3072, 512);

    // Q gets the 1/sqrt(256) attention scale folded in for free
    norm_rope_kernel<<<8192, 256, 0, stream>>>(C, qro, qnw, cosb, sinb, 8,
                                               3072L, 0L, 4194304L, 256L, 2048L, 0.0625f);
    norm_rope_kernel<<<2048, 256, 0, stream>>>(C, kr, knw, cosb, sinb, 2,
                                               3072L, 2048L, 1048576L, 524288L, 256L, 1.0f);
    transpose_v_kernel<<<dim3(32, 4, 4), 256, 0, stream>>>(C, vr);

    flash_kernel<<<256, 512, 0, stream>>>(qro, kr, vr, ao);

    gemm_bt<64, 0><<<dim3(8, 32), 256, 0, stream>>>(ao, wot, out, 4096, 512, 2048);
}

// Round 8
// 199.903 us; speedup vs baseline: 1.4248x; 1.0783x over previous
//
#include <hip/hip_runtime.h>

#define S_LEN 2048
#define NHQ 8
#define NKV 2
#define HD 256
#define KVB 32

typedef __attribute__((ext_vector_type(8))) short bf16x8;
typedef __attribute__((ext_vector_type(4))) short bf16x4;
typedef __attribute__((ext_vector_type(4))) float f32x4;
typedef __attribute__((ext_vector_type(16))) float f32x16;
typedef __attribute__((ext_vector_type(4))) unsigned u32x4;

__device__ __forceinline__ short f2bf(float f) {
    unsigned u = __builtin_bit_cast(unsigned, f);
    u += 0x7FFFu + ((u >> 16) & 1u);
    return (short)(u >> 16);
}
__device__ __forceinline__ float bf2f(short s) {
    unsigned u = ((unsigned)(unsigned short)s) << 16;
    return __builtin_bit_cast(float, u);
}
__device__ __forceinline__ unsigned cvtpk(float a, float b) {
    unsigned r;
    asm("v_cvt_pk_bf16_f32 %0, %1, %2" : "=v"(r) : "v"(a), "v"(b));
    return r;
}
__device__ __forceinline__ void gload16(const short* g, short* l) {
    __builtin_amdgcn_global_load_lds((const __attribute__((address_space(1))) unsigned*)g,
                                     (__attribute__((address_space(3))) unsigned*)l, 16, 0, 0);
}
__device__ __forceinline__ float bperm(int srclane, float v) {
    return __builtin_bit_cast(float,
        __builtin_amdgcn_ds_bpermute(srclane * 4, __builtin_bit_cast(int, v)));
}

// ---------------- fp32 -> bf16 convert ----------------
__global__ __launch_bounds__(256) void cvt_kernel(const float* __restrict__ in,
                                                  short* __restrict__ out, int n) {
    int i = (blockIdx.x * 256 + threadIdx.x) * 4;
    if (i + 3 < n) {
        float4 f = *(const float4*)(in + i);
        bf16x4 o;
        o[0] = f2bf(f.x); o[1] = f2bf(f.y); o[2] = f2bf(f.z); o[3] = f2bf(f.w);
        *(bf16x4*)(out + i) = o;
    }
}

// ---------------- fp32 W[K][N] -> bf16 Wt[N][K] (convert + transpose) -------
__global__ __launch_bounds__(256) void wt_kernel(const float* __restrict__ in,
                                                 short* __restrict__ out,
                                                 int K, int N) {
    __shared__ short tile[64][72];
    int n0 = blockIdx.x * 64, k0 = blockIdx.y * 64;
    int t = threadIdx.x;
    #pragma unroll
    for (int i = 0; i < 16; i++) {
        int flat = i * 256 + t; int r = flat >> 6, c = flat & 63;
        tile[r][c] = f2bf(in[(long)(k0 + r) * N + n0 + c]);
    }
    __syncthreads();
    #pragma unroll
    for (int i = 0; i < 16; i++) {
        int flat = i * 256 + t; int r = flat >> 6, c = flat & 63;
        out[(long)(n0 + r) * K + k0 + c] = tile[c][r];
    }
}

// ---------------- m97-style GEMM: C[M][N] = A[M][K] @ Bt[N][K]^T ------------
template<int BN, int WRITE_BF16>
__global__ __launch_bounds__(256) void gemm_bt(const short* __restrict__ A,
                                               const short* __restrict__ Bt,
                                               void* __restrict__ Cv,
                                               int M, int N, int K) {
    constexpr int NI = BN / 32;          // B-frags per wave
    __shared__ short As[128 * 32];
    __shared__ short Bs[BN * 32];
    const int t = threadIdx.x;
    const int lane = t & 63, w = t >> 6;
    const int lr = lane & 15, lg = lane >> 4;
    const int m0 = blockIdx.y * 128, n0 = blockIdx.x * BN;
    const int wm = (w >> 1) * 64, wn = (w & 1) * (BN / 2);

    f32x4 acc[4][NI];
    #pragma unroll
    for (int i = 0; i < 4; i++)
        #pragma unroll
        for (int j = 0; j < NI; j++) acc[i][j] = (f32x4){0.f, 0.f, 0.f, 0.f};

    for (int k0 = 0; k0 < K; k0 += 32) {
        __syncthreads();
        #pragma unroll
        for (int r = 0; r < 2; r++) {            // A tile: 128x32 = 8 KB
            int sbase = r * 2048 + w * 512;
            int srow = (sbase + lane * 8) >> 5, scol = (sbase + lane * 8) & 31;
            gload16(A + (long)(m0 + srow) * K + k0 + scol, &As[sbase]);
        }
        #pragma unroll
        for (int r = 0; r < BN / 64; r++) {      // B tile: BNx32
            int sbase = r * 2048 + w * 512;
            int srow = (sbase + lane * 8) >> 5, scol = (sbase + lane * 8) & 31;
            gload16(Bt + (long)(n0 + srow) * K + k0 + scol, &Bs[sbase]);
        }
        __syncthreads();
        bf16x8 af[4], bfr[NI];
        #pragma unroll
        for (int mi = 0; mi < 4; mi++)
            af[mi] = *(const bf16x8*)&As[(wm + mi * 16 + lr) * 32 + lg * 8];
        #pragma unroll
        for (int ni = 0; ni < NI; ni++)
            bfr[ni] = *(const bf16x8*)&Bs[(wn + ni * 16 + lr) * 32 + lg * 8];
        #pragma unroll
        for (int mi = 0; mi < 4; mi++)
            #pragma unroll
            for (int ni = 0; ni < NI; ni++)
                acc[mi][ni] = __builtin_amdgcn_mfma_f32_16x16x32_bf16(af[mi], bfr[ni], acc[mi][ni], 0, 0, 0);
    }
    #pragma unroll
    for (int mi = 0; mi < 4; mi++)
    #pragma unroll
    for (int ni = 0; ni < NI; ni++)
    #pragma unroll
    for (int r = 0; r < 4; r++) {
        long row = m0 + wm + mi * 16 + lg * 4 + r;
        long col = n0 + wn + ni * 16 + lr;
        float v = acc[mi][ni][r];
        if (WRITE_BF16) ((short*)Cv)[row * N + col] = f2bf(v);
        else            ((float*)Cv)[row * N + col] = v;
    }
}

// ---------------- RMSNorm + partial RoPE (+ optional score prescale) --------
// reads strided rows from the fused QKV output C
__global__ __launch_bounds__(256) void norm_rope_kernel(
    const short* __restrict__ in, short* __restrict__ out,
    const float* __restrict__ w, const float* __restrict__ cosb,
    const float* __restrict__ sinb, int H, long ldin, long cofs,
    long ob, long oh, long os, float scale) {
    int vec = blockIdx.x * 4 + (threadIdx.x >> 6);
    int lane = threadIdx.x & 63;
    int token = vec / H, head = vec % H;
    int b = token / S_LEN, s = token % S_LEN;

    bf16x4 xv = *(const bf16x4*)(in + (long)token * ldin + cofs + head * 256 + lane * 4);
    float x0 = bf2f(xv[0]), x1 = bf2f(xv[1]), x2 = bf2f(xv[2]), x3 = bf2f(xv[3]);
    float ss = x0 * x0 + x1 * x1 + x2 * x2 + x3 * x3;
    #pragma unroll
    for (int m = 1; m < 64; m <<= 1) ss += __shfl_xor(ss, m);
    float inv = rsqrtf(ss * (1.f / 256.f) + 1e-6f);

    float4 wv = *(const float4*)(w + lane * 4);
    float y0 = x0 * inv * (1.f + wv.x);
    float y1 = x1 * inv * (1.f + wv.y);
    float y2 = x2 * inv * (1.f + wv.z);
    float y3 = x3 * inv * (1.f + wv.w);

    if (lane < 16) {
        float2 c = *(const float2*)&cosb[s * 32 + lane * 2];
        float2 sn = *(const float2*)&sinb[s * 32 + lane * 2];
        float a0 = y0 * c.x - y1 * sn.x, b0 = y0 * sn.x + y1 * c.x;
        float a1 = y2 * c.y - y3 * sn.y, b1 = y2 * sn.y + y3 * c.y;
        y0 = a0; y1 = b0; y2 = a1; y3 = b1;
    }
    y0 *= scale; y1 *= scale; y2 *= scale; y3 *= scale;
    long oidx = (long)b * ob + (long)head * oh + (long)s * os + lane * 4;
    bf16x4 o; o[0] = f2bf(y0); o[1] = f2bf(y1); o[2] = f2bf(y2); o[3] = f2bf(y3);
    *(bf16x4*)(out + oidx) = o;
}

// ---------------- V transpose: C[token][2560+kv*256+d] -> vr[b][kv][d][s] ---
__global__ __launch_bounds__(256) void transpose_v_kernel(const short* __restrict__ C,
                                                          short* __restrict__ vr) {
    __shared__ short tile[64][65];
    int s0 = blockIdx.x * 64, d0 = blockIdx.y * 64;
    int bkv = blockIdx.z; int b = bkv >> 1, kv = bkv & 1;
    int t = threadIdx.x;
    #pragma unroll
    for (int i = 0; i < 16; i++) {
        int flat = i * 256 + t; int si = flat >> 6, di = flat & 63;
        tile[si][di] = C[(long)(b * S_LEN + s0 + si) * 3072 + 2560 + kv * 256 + d0 + di];
    }
    __syncthreads();
    #pragma unroll
    for (int i = 0; i < 16; i++) {
        int flat = i * 256 + t; int di = flat >> 6, si = flat & 63;
        vr[(long)(bkv * 256 + d0 + di) * S_LEN + s0 + si] = tile[si][di];
    }
}

// ---------------- flash attention: 4-wave blocks, 64 q-rows, uniform work ---
// Block = chunk j (64 rows): 2 q-groups x 2 key-parities. j+1 phases each.
// 64 KB LDS -> 2 blocks/CU co-resident; XCD-aware bh mapping (4MB KV per XCD).
// Scores pre-scaled by 1/16 (folded into Q).
__global__ __launch_bounds__(256, 2) void flash_kernel(const short* __restrict__ Q,
                                                       const short* __restrict__ Kt,
                                                       const short* __restrict__ Vt,
                                                       short* __restrict__ O) {
    // [0,32K): K tiles (parity p at p*16KB); [32K,64K): V tiles; epilogue reuses
    __shared__ __align__(16) char smem[66048];

    int idx = blockIdx.x;
    int xcd = idx & 7, slot = idx >> 3;      // consecutive blocks -> XCD round-robin
    int bh = xcd * 2 + (slot & 1);           // 2 bh per XCD -> 4MB KV in its L2
    int j  = 31 - (slot >> 1);               // chunk 0..31, heavy first
    int h = bh & 7, b = bh >> 3;
    int kv = h >> 2;
    int t = threadIdx.x, lane = t & 63, w = t >> 6;
    int g = w >> 1, p = w & 1;               // q-group, key parity
    int ln = lane & 31, hi = lane >> 5;
    int q0 = j * 64 + g * 32;
    int qg = q0 + ln;                        // this lane's q row (score column)

    const short* Kb = Kt + (long)(b * NKV + kv) * S_LEN * HD;
    const short* Vb = Vt + (long)(b * NKV + kv) * HD * S_LEN;

    // Q fragments in registers: Q[q=ln][dc*16 + hi*8 + e]
    bf16x8 qf[16];
    {
        const short* qrow = Q + ((long)(b * S_LEN + qg) * NHQ + h) * HD + hi * 8;
        #pragma unroll
        for (int dc = 0; dc < 16; dc++) qf[dc] = *(const bf16x8*)&qrow[dc * 16];
    }

    f32x16 acc[8];
    #pragma unroll
    for (int i = 0; i < 8; i++)
        #pragma unroll
        for (int jj = 0; jj < 16; jj++) acc[i][jj] = 0.f;
    float m = -1e30f, l = 0.f;

    // stage tiles {2*ph2, 2*ph2+1} into parity slots 0/1 (16 loads/thread)
    auto stage = [&](int ph2) {
        #pragma unroll
        for (int pp = 0; pp < 2; pp++) {
            int k0s = (2 * ph2 + pp) * KVB;
            short* Ktile = (short*)(smem + pp * 16384);
            short* Vtile = (short*)(smem + 32768 + pp * 16384);
            #pragma unroll
            for (int c = 0; c < 4; c++) {
                int o = c * 4096 + w * 1024 + lane * 16;   // byte offset in tile
                int key = o >> 9, db = o & 511;
                gload16(Kb + (long)(k0s + key) * HD + ((db ^ ((key & 7) << 4)) >> 1),
                        Ktile + (c * 4096 + w * 1024) / 2);
                int d = o >> 6, kb = o & 63;
                gload16(Vb + (long)d * S_LEN + k0s + ((kb ^ ((d & 6) << 3)) >> 1),
                        Vtile + (c * 4096 + w * 1024) / 2);
            }
        }
    };

    auto compute = [&](int k0) {
        const char* Ks = (const char*)smem + p * 16384;
        const char* Vs = (const char*)smem + 32768 + p * 16384;
        // ---- QK^T (swapped): s = K * Q, D[key][q]; 2 chains ----
        f32x16 sA, sB;
        #pragma unroll
        for (int r = 0; r < 16; r++) { sA[r] = 0.f; sB[r] = 0.f; }
        __builtin_amdgcn_s_setprio(1);
        #pragma unroll
        for (int dc = 0; dc < 16; dc += 2) {
            int kb0 = (dc * 32 + hi * 16) ^ ((ln & 7) << 4);
            int kb1 = ((dc + 1) * 32 + hi * 16) ^ ((ln & 7) << 4);
            bf16x8 kf0 = *(const bf16x8*)(Ks + ln * 512 + kb0);
            bf16x8 kf1 = *(const bf16x8*)(Ks + ln * 512 + kb1);
            sA = __builtin_amdgcn_mfma_f32_32x32x16_bf16(kf0, qf[dc],     sA, 0, 0, 0);
            sB = __builtin_amdgcn_mfma_f32_32x32x16_bf16(kf1, qf[dc + 1], sB, 0, 0, 0);
        }
        __builtin_amdgcn_s_setprio(0);
        f32x16 s;
        #pragma unroll
        for (int r = 0; r < 16; r++) s[r] = sA[r] + sB[r];

        // ---- mask + online softmax, fully in-register ----
        if (k0 + KVB - 1 > q0) {
            #pragma unroll
            for (int r = 0; r < 16; r++) {
                int key_g = k0 + (r & 3) + 8 * (r >> 2) + 4 * hi;
                if (key_g > qg) s[r] = -1e30f;
            }
        }
        float mt = s[0];
        #pragma unroll
        for (int r = 1; r < 16; r++) mt = fmaxf(mt, s[r]);
        mt = fmaxf(mt, __shfl_xor(mt, 32));
        float mn = m;
        if (!__all(mt <= m + 8.f)) {           // defer-max (T13)
            mn = fmaxf(m, mt);
            float f = __expf(m - mn);
            m = mn;
            float fr[16];
            #pragma unroll
            for (int r = 0; r < 16; r++)
                fr[r] = bperm((r & 3) + 8 * (r >> 2) + 4 * hi, f);
            #pragma unroll
            for (int i = 0; i < 8; i++)
                #pragma unroll
                for (int r = 0; r < 16; r++) acc[i][r] *= fr[r];
            l *= f;
        }
        float pr[16], ps = 0.f;
        #pragma unroll
        for (int r = 0; r < 16; r++) { pr[r] = __expf(s[r] - mn); ps += pr[r]; }
        ps += __shfl_xor(ps, 32);
        l += ps;

        // ---- P -> bf16 A-fragments via cvt_pk + permlane32_swap (T12) ----
        unsigned pw[8];
        #pragma unroll
        for (int kc = 0; kc < 2; kc++) {
            unsigned X = cvtpk(pr[kc * 8 + 0], pr[kc * 8 + 1]);
            unsigned Y = cvtpk(pr[kc * 8 + 4], pr[kc * 8 + 5]);
            unsigned Z = cvtpk(pr[kc * 8 + 2], pr[kc * 8 + 3]);
            unsigned W = cvtpk(pr[kc * 8 + 6], pr[kc * 8 + 7]);
            asm volatile("v_permlane32_swap_b32 %0, %1" : "+v"(X), "+v"(Y));
            asm volatile("v_permlane32_swap_b32 %0, %1" : "+v"(Z), "+v"(W));
            pw[kc * 4 + 0] = X; pw[kc * 4 + 1] = Z;
            pw[kc * 4 + 2] = Y; pw[kc * 4 + 3] = W;
        }
        u32x4 w0v = {pw[0], pw[1], pw[2], pw[3]};
        u32x4 w1v = {pw[4], pw[5], pw[6], pw[7]};
        bf16x8 pa0 = __builtin_bit_cast(bf16x8, w0v);
        bf16x8 pa1 = __builtin_bit_cast(bf16x8, w1v);

        // ---- PV: acc[db] += P * V, D[q][d], lane owns d column ----
        __builtin_amdgcn_s_setprio(1);
        #pragma unroll
        for (int db = 0; db < 8; db++) {
            int drow = db * 32 + ln;
            int sw = (drow & 6) << 3;
            bf16x8 vf0 = *(const bf16x8*)(Vs + drow * 64 + ((hi * 16) ^ sw));
            bf16x8 vf1 = *(const bf16x8*)(Vs + drow * 64 + ((32 + hi * 16) ^ sw));
            acc[db] = __builtin_amdgcn_mfma_f32_32x32x16_bf16(pa0, vf0, acc[db], 0, 0, 0);
            acc[db] = __builtin_amdgcn_mfma_f32_32x32x16_bf16(pa1, vf1, acc[db], 0, 0, 0);
        }
        __builtin_amdgcn_s_setprio(0);
    };

    stage(0);
    for (int ph = 0; ph <= j; ph++) {
        asm volatile("s_waitcnt vmcnt(0)" ::: "memory");
        __builtin_amdgcn_s_barrier();
        int k0 = (2 * ph + p) * KVB;
        if (k0 <= q0 + 31) compute(k0);      // skip only fully-masked diagonal tile
        __builtin_amdgcn_s_barrier();
        if (ph < j) stage(ph + 1);
        __builtin_amdgcn_sched_barrier(0);
    }

    // ---- parity merge epilogue (staging LDS is dead) ----
    float* accb = (float*)smem;                 // [g][128][64] f32
    float* mlb  = (float*)(smem + 65536);       // m: [0,64), l: [64,128)
    if (p == 1) {
        #pragma unroll
        for (int db = 0; db < 8; db++)
            #pragma unroll
            for (int r = 0; r < 16; r++)
                accb[g * 8192 + (db * 16 + r) * 64 + hi * 32 + ln] = acc[db][r];
        if (hi == 0) { mlb[g * 32 + ln] = m; mlb[64 + g * 32 + ln] = l; }
    }
    __syncthreads();
    if (p == 0) {
        float m1 = mlb[g * 32 + ln], l1 = mlb[64 + g * 32 + ln];
        float M  = fmaxf(m, m1);
        float f0 = __expf(m - M), f1 = __expf(m1 - M);
        float lt = l * f0 + l1 * f1;
        float w0 = f0 / lt, w1 = f1 / lt;
        float fr0[16], fr1[16];
        #pragma unroll
        for (int r = 0; r < 16; r++) {
            int crow = (r & 3) + 8 * (r >> 2) + 4 * hi;
            fr0[r] = bperm(crow, w0);
            fr1[r] = bperm(crow, w1);
        }
        #pragma unroll
        for (int db = 0; db < 8; db++)
            #pragma unroll
            for (int r = 0; r < 16; r++) {
                float a1 = accb[g * 8192 + (db * 16 + r) * 64 + hi * 32 + ln];
                int qrow = q0 + (r & 3) + 8 * (r >> 2) + 4 * hi;
                O[(long)(b * S_LEN + qrow) * 2048 + h * HD + db * 32 + ln] =
                    f2bf(acc[db][r] * fr0[r] + a1 * fr1[r]);
            }
    }
}

extern "C" void kernel_launch(void* const* d_in, const int* in_sizes, int n_in,
                              void* d_out, int out_size, void* d_ws, size_t ws_size,
                              hipStream_t stream) {
    const float* x    = (const float*)d_in[0];
    const float* cosb = (const float*)d_in[1];
    const float* sinb = (const float*)d_in[2];
    // d_in[3] = mask: equivalent to causal; computed analytically in-kernel
    const float* wq   = (const float*)d_in[4];
    const float* wk   = (const float*)d_in[5];
    const float* wv   = (const float*)d_in[6];
    const float* wo   = (const float*)d_in[7];
    const float* qnw  = (const float*)d_in[8];
    const float* knw  = (const float*)d_in[9];
    float* out = (float*)d_out;

    char* ws = (char*)d_ws;
    short* xb   = (short*)(ws + 0);          // 4096x512 bf16               [0, 4194304)
    short* wfus = (short*)(ws + 4194304);    // [3072][512] wq|wk|wv^T      [4194304, 7340032)
    short* wot  = (short*)(ws + 7340032);    // [512][2048] wo^T            [7340032, 9437184)
    short* C    = (short*)(ws + 9437184);    // 4096x3072 fused QKV out     [9437184, 34603008)
    short* ao   = (short*)(ws + 9437184);    // flash out aliases C (dead)
    short* qro  = (short*)(ws + 34603008);   // 4096x2048 roped Q           [34603008, 51380224)
    short* kr   = (short*)(ws + 51380224);   // [b][kv][s][d] 4 MB          [51380224, 55574528)
    short* vr   = (short*)(ws + 55574528);   // [b][kv][d][s] 4 MB          [55574528, 59768832)

    cvt_kernel<<<2048, 256, 0, stream>>>(x, xb, 2097152);
    wt_kernel<<<dim3(32, 8), 256, 0, stream>>>(wq, wfus,              512, 2048);
    wt_kernel<<<dim3(8, 8),  256, 0, stream>>>(wk, wfus + 2048 * 512, 512, 512);
    wt_kernel<<<dim3(8, 8),  256, 0, stream>>>(wv, wfus + 2560 * 512, 512, 512);
    wt_kernel<<<dim3(8, 32), 256, 0, stream>>>(wo, wot, 2048, 512);

    // fused QKV projection: C[4096][3072]
    gemm_bt<128, 1><<<dim3(24, 32), 256, 0, stream>>>(xb, wfus, C, 4096, 3072, 512);

    // Q gets the 1/sqrt(256) attention scale folded in for free
    norm_rope_kernel<<<8192, 256, 0, stream>>>(C, qro, qnw, cosb, sinb, 8,
                                               3072L, 0L, 4194304L, 256L, 2048L, 0.0625f);
    norm_rope_kernel<<<2048, 256, 0, stream>>>(C, kr, knw, cosb, sinb, 2,
                                               3072L, 2048L, 1048576L, 524288L, 256L, 1.0f);
    transpose_v_kernel<<<dim3(32, 4, 4), 256, 0, stream>>>(C, vr);

    flash_kernel<<<512, 256, 0, stream>>>(qro, kr, vr, ao);

    gemm_bt<64, 0><<<dim3(8, 32), 256, 0, stream>>>(ao, wot, out, 4096, 512, 2048);
}